// Round 4
// baseline (695.894 us; speedup 1.0000x reference)
//
#include <hip/hip_runtime.h>
#include <stdint.h>

// ---------------------------------------------------------------------------
// ConditionedCTKoopmanTransition: d=512, u=32, n_obs=50, B=512, T=256
// v5:
//   1. k_mmbig: 512 threads / 8 waves (2Mx4N), same 128x128/BK64/dbuf/swizzle
//      dataflow -> 16 waves/CU (was 8), double TLP, half per-wave staging.
//   2. k_build_M / k_extract: LDS 32x32 tile transposes -> coalesced XBt/PT1.
//   3. k_packX / k_assembleUW: 4-wide ushort4 vectorization.
//   expm chain (s=2 + degree-7 PS, split-bf16) unchanged — validated.
// ---------------------------------------------------------------------------

typedef __bf16 bf16x8 __attribute__((ext_vector_type(8)));
typedef float  f32x4  __attribute__((ext_vector_type(4)));

#define NE  576
#define NE3 1728   // 3*NE (split-bf16: [hi|hi|lo] x [hi|lo|hi])

__device__ __forceinline__ unsigned short f2bf(float x){
  union { float f; unsigned int u; } v; v.f = x;
  unsigned int r = (v.u + 0x7fffu + ((v.u >> 16) & 1u)) >> 16;
  return (unsigned short)r;
}
__device__ __forceinline__ float bf2f(unsigned short h){
  union { float f; unsigned int u; } v; v.u = ((unsigned int)h) << 16;
  return v.f;
}

__device__ __forceinline__ void gll16(const void* g, void* l){
  __builtin_amdgcn_global_load_lds((__attribute__((address_space(1))) void*)g,
                                   (__attribute__((address_space(3))) void*)l,
                                   16, 0, 0);
}

// ---------------------------------------------------------------------------
// build scaled augmented matrix X = Maug * dt / 4, f32 + split forms.
// Tiled 32x32 with LDS transpose so XBt writes are coalesced.
// ---------------------------------------------------------------------------
__global__ __launch_bounds__(256) void k_build_M(
    const float* __restrict__ skew, const float* __restrict__ gamma,
    const float* __restrict__ dtp, const float* __restrict__ B_ct,
    float* __restrict__ Xf, unsigned short* __restrict__ XAp,
    unsigned short* __restrict__ XBt){
  __shared__ float T[32][33];
  int bx = blockIdx.x % 18, by = blockIdx.x / 18;
  int r0 = by * 32, c0 = bx * 32;
  int tr = threadIdx.x >> 5, tc = threadIdx.x & 31;   // 8 x 32
  float sc = dtp[0] * 0.25f;     // s=2 scaling
  #pragma unroll
  for (int p = 0; p < 4; p++) {
    int r = r0 + p * 8 + tr, c = c0 + tc;
    float v = 0.f;
    if (r < 512 && c < 512) {
      if (r < c) {
        long k = 511L * r - (long)r * (r - 1) / 2 + (c - r - 1);
        v = skew[k];
      } else if (r > c) {
        long k = 511L * c - (long)c * (c - 1) / 2 + (r - c - 1);
        v = -skew[k];
      } else {
        float g = gamma[r];
        float sp = (g > 20.f) ? g : log1pf(expf(g));
        v = -sp;
      }
    } else if (r < 512 && c >= 512 && c < 544) {
      v = B_ct[r * 32 + (c - 512)];
    }
    v *= sc;
    long id = (long)r * NE + c;
    Xf[id] = v;
    unsigned short hi = f2bf(v);
    unsigned short lo = f2bf(v - bf2f(hi));
    XAp[(long)r * NE3 + c]          = hi;
    XAp[(long)r * NE3 + NE + c]     = hi;
    XAp[(long)r * NE3 + 2 * NE + c] = lo;
    T[p * 8 + tr][tc] = v;
  }
  __syncthreads();
  #pragma unroll
  for (int p = 0; p < 4; p++) {
    int cl = p * 8 + tr, rl = tc;
    float v = T[rl][cl];
    unsigned short hi = f2bf(v);
    unsigned short lo = f2bf(v - bf2f(hi));
    long base = (long)(c0 + cl) * NE3 + r0;
    XBt[base + rl]          = hi;
    XBt[base + NE + rl]     = lo;
    XBt[base + 2 * NE + rl] = hi;
  }
}

// ---------------------------------------------------------------------------
// split-bf16 GEMM for expm: C(576x576) = A*B (+Cadd), K=1728, BK=192,
// dbuf + swizzle + counted vmcnt.
// ---------------------------------------------------------------------------
__global__ __launch_bounds__(256) void k_expm_gemm(
    const unsigned short* __restrict__ Ap, const unsigned short* __restrict__ Bt,
    const float* __restrict__ Cadd, float* __restrict__ outF,
    unsigned short* __restrict__ outAp, unsigned short* __restrict__ outBt){
  __shared__ __align__(16) unsigned short As[2][32 * 192];
  __shared__ __align__(16) unsigned short Bs[2][32 * 192];
  int tid = threadIdx.x, wave = tid >> 6, lane = tid & 63;
  int wm = wave & 1, wn = wave >> 1;
  int m0 = blockIdx.y * 32, n0 = blockIdx.x * 32;
  int lr = lane & 15, kq = lane >> 4;
  f32x4 acc = {0.f, 0.f, 0.f, 0.f};
  auto stage = [&](int buf, int kt){
    #pragma unroll
    for (int i = 0; i < 3; i++) {
      int base = i * 256 + wave * 64;     // wave-uniform LDS base
      int cc = base + lane;
      int rr = cc / 24, sl = cc - rr * 24;
      int ss = (sl & 24) | ((sl & 7) ^ (rr & 7));
      gll16(Ap + (long)(m0 + rr) * NE3 + kt + ss * 8, &As[buf][base * 8]);
      gll16(Bt + (long)(n0 + rr) * NE3 + kt + ss * 8, &Bs[buf][base * 8]);
    }
  };
  stage(0, 0);
  int cur = 0;
  for (int kt = 0; kt < NE3; kt += 192) {
    if (kt + 192 < NE3) {
      stage(cur ^ 1, kt + 192);
      asm volatile("s_waitcnt vmcnt(6)" ::: "memory");
    } else {
      asm volatile("s_waitcnt vmcnt(0)" ::: "memory");
    }
    __builtin_amdgcn_s_barrier();
    __builtin_amdgcn_sched_barrier(0);
    #pragma unroll
    for (int hh = 0; hh < 6; hh++) {
      int eo = (hh * 32 + kq * 8) ^ ((lr & 7) << 3);
      bf16x8 af = *(const bf16x8*)&As[cur][(wm * 16 + lr) * 192 + eo];
      bf16x8 bf = *(const bf16x8*)&Bs[cur][(wn * 16 + lr) * 192 + eo];
      acc = __builtin_amdgcn_mfma_f32_16x16x32_bf16(af, bf, acc, 0, 0, 0);
    }
    __builtin_amdgcn_s_barrier();
    cur ^= 1;
  }
  int n = n0 + wn * 16 + lr;
  for (int i = 0; i < 4; i++) {
    int m = m0 + wm * 16 + kq * 4 + i;
    float v = acc[i];
    if (Cadd) v += Cadd[(long)m * NE + n];
    if (outF) outF[(long)m * NE + n] = v;
    unsigned short hi = f2bf(v);
    unsigned short lo = f2bf(v - bf2f(hi));
    if (outAp) {
      outAp[(long)m * NE3 + n]          = hi;
      outAp[(long)m * NE3 + NE + n]     = hi;
      outAp[(long)m * NE3 + 2 * NE + n] = lo;
    }
    if (outBt) {
      outBt[(long)n * NE3 + m]          = hi;
      outBt[(long)n * NE3 + NE + m]     = lo;
      outBt[(long)n * NE3 + 2 * NE + m] = hi;
    }
  }
}

// ---------------------------------------------------------------------------
// degree-7 PS coefficients: B0 (f32 Cadd), B1 (split Ap).  E = B1*X4 + B0
// ---------------------------------------------------------------------------
__global__ __launch_bounds__(256) void k_poly(
    const float* __restrict__ Xf, const float* __restrict__ X2f,
    const float* __restrict__ X3f, float* __restrict__ B0,
    unsigned short* __restrict__ B1Ap){
  int id = blockIdx.x * 256 + threadIdx.x;
  if (id >= NE * NE) return;
  int r = id / NE, c = id % NE;
  float x = Xf[id], x2 = X2f[id], x3 = X3f[id];
  float ii = (r == c) ? 1.f : 0.f;
  float b0 = ii + x + x2 * 0.5f + x3 * (1.f / 6.f);
  float b1 = ii * (1.f / 24.f) + x * (1.f / 120.f) + x2 * (1.f / 720.f) + x3 * (1.f / 5040.f);
  B0[id] = b0;
  unsigned short hi = f2bf(b1), lo = f2bf(b1 - bf2f(hi));
  B1Ap[(long)r * NE3 + c]          = hi;
  B1Ap[(long)r * NE3 + NE + c]     = hi;
  B1Ap[(long)r * NE3 + 2 * NE + c] = lo;
}

// ---------------------------------------------------------------------------
// extract A_bar/B_bar from expm result; padded C (64 rows) as CA block 0.
// Tiled 32x32 with LDS transpose so PT1 writes/reads are coalesced.
// ---------------------------------------------------------------------------
__global__ __launch_bounds__(256) void k_extract(
    const float* __restrict__ F, const float* __restrict__ Cin,
    unsigned short* __restrict__ WbigT, unsigned short* __restrict__ PT1,
    unsigned short* __restrict__ BbarT, unsigned short* __restrict__ G0,
    unsigned short* __restrict__ CA0){
  int b = blockIdx.x;
  if (b < 256) {
    __shared__ float T[32][33];
    int by = b >> 4, bx = b & 15;
    int m0 = by * 32, k0 = bx * 32;
    int tr = threadIdx.x >> 5, tc = threadIdx.x & 31;
    #pragma unroll
    for (int p = 0; p < 4; p++) {
      int m = m0 + p * 8 + tr, k = k0 + tc;
      float v = F[(long)m * NE + k];
      WbigT[(long)m * 1024 + k] = f2bf(v);
      T[p * 8 + tr][tc] = v;
    }
    __syncthreads();
    #pragma unroll
    for (int p = 0; p < 4; p++) {
      int kl = p * 8 + tr, ml = tc;
      PT1[(long)(k0 + kl) * 512 + m0 + ml] = f2bf(T[ml][kl]);
    }
  } else {
    int id0 = (b - 256) * 256 + threadIdx.x;
    for (int id = id0; id < 64 * 512; id += 1024) {
      if (id < 512 * 32) {
        int dd = id >> 5, u = id & 31;
        unsigned short h = f2bf(F[(long)dd * NE + 512 + u]);
        G0[id] = h;                         // B_bar row-major (512x32)
        BbarT[(long)u * 512 + dd] = h;      // B_bar^T (32x512)
      }
      CA0[id] = (id < 50 * 512) ? f2bf(Cin[id]) : (unsigned short)0;
    }
  }
}

// ---------------------------------------------------------------------------
// generic bf16 "bt" GEMM, BK=64, dbuf+swizzle+counted vmcnt:
//   C[m,n] = sum_k A[m,k]*Bt[n,k]; optional transpose output outT = C^T.
// ---------------------------------------------------------------------------
template<int BM, int BN, int WM, int WN>
__global__ __launch_bounds__(256) void k_btgemm(
    const unsigned short* __restrict__ A, int ldA, long sAz,
    const unsigned short* __restrict__ Bt, int ldB, long sBz,
    unsigned short* __restrict__ C, int ldC, long sCz, int K,
    unsigned short* __restrict__ outT, int ldT, long sTz){
  constexpr int FM = BM / (16 * WM), FN = BN / (16 * WN);
  constexpr int LA = BM / 32, LB = BN / 32;
  __shared__ __align__(16) unsigned short As[2][BM * 64];
  __shared__ __align__(16) unsigned short Bs[2][BN * 64];
  int tid = threadIdx.x, wave = tid >> 6, lane = tid & 63;
  int wm = wave % WM, wn = wave / WM;
  long z = blockIdx.z;
  const unsigned short* Ab = A + z * sAz;
  const unsigned short* Bb = Bt + z * sBz;
  int m0 = blockIdx.y * BM, n0 = blockIdx.x * BN;
  int lr = lane & 15, kq = lane >> 4;
  f32x4 acc[FM][FN];
  f32x4 z4 = {0.f, 0.f, 0.f, 0.f};
  for (int i = 0; i < FM; i++) for (int j = 0; j < FN; j++) acc[i][j] = z4;
  auto stage = [&](int buf, int kt){
    #pragma unroll
    for (int i = 0; i < LA; i++) {
      int base = i * 256 + wave * 64;
      int cc = base + lane; int rr = cc >> 3, sl = cc & 7;
      gll16(Ab + (long)(m0 + rr) * ldA + kt + ((sl ^ (rr & 7)) << 3), &As[buf][base * 8]);
    }
    #pragma unroll
    for (int i = 0; i < LB; i++) {
      int base = i * 256 + wave * 64;
      int cc = base + lane; int rr = cc >> 3, sl = cc & 7;
      gll16(Bb + (long)(n0 + rr) * ldB + kt + ((sl ^ (rr & 7)) << 3), &Bs[buf][base * 8]);
    }
  };
  stage(0, 0);
  int cur = 0;
  for (int kt = 0; kt < K; kt += 64) {
    if (kt + 64 < K) {
      stage(cur ^ 1, kt + 64);
      asm volatile("s_waitcnt vmcnt(%0)" :: "i"(LA + LB) : "memory");
    } else {
      asm volatile("s_waitcnt vmcnt(0)" ::: "memory");
    }
    __builtin_amdgcn_s_barrier();
    __builtin_amdgcn_sched_barrier(0);
    #pragma unroll
    for (int h = 0; h < 2; h++) {
      int eo = (h * 32 + kq * 8) ^ ((lr & 7) << 3);
      bf16x8 af[FM], bfr[FN];
      #pragma unroll
      for (int i = 0; i < FM; i++)
        af[i] = *(const bf16x8*)&As[cur][(wm * (16 * FM) + i * 16 + lr) * 64 + eo];
      #pragma unroll
      for (int j = 0; j < FN; j++)
        bfr[j] = *(const bf16x8*)&Bs[cur][(wn * (16 * FN) + j * 16 + lr) * 64 + eo];
      #pragma unroll
      for (int i = 0; i < FM; i++)
        #pragma unroll
        for (int j = 0; j < FN; j++)
          acc[i][j] = __builtin_amdgcn_mfma_f32_16x16x32_bf16(af[i], bfr[j], acc[i][j], 0, 0, 0);
    }
    __builtin_amdgcn_s_barrier();
    cur ^= 1;
  }
  unsigned short* Cb = C + z * sCz;
  unsigned short* Tb = outT ? outT + z * sTz : nullptr;
  for (int i = 0; i < FM; i++)
    for (int j = 0; j < FN; j++) {
      int n = n0 + wn * (16 * FN) + j * 16 + lr;
      for (int r = 0; r < 4; r++) {
        int m = m0 + wm * (16 * FM) + i * 16 + kq * 4 + r;
        unsigned short hv = f2bf(acc[i][j][r]);
        Cb[(long)m * ldC + n] = hv;
        if (Tb) Tb[(long)n * ldT + m] = hv;
      }
    }
}

// ---------------------------------------------------------------------------
// merged fill of U-region (rows 0..8191) and Y-region (rows 8192..9215),
// 4-wide vectorized.
// ---------------------------------------------------------------------------
__global__ __launch_bounds__(256) void k_assembleUW(
    const unsigned short* __restrict__ G, const unsigned short* __restrict__ CA,
    const unsigned short* __restrict__ CG, const float* __restrict__ Din,
    const float* __restrict__ dtp, unsigned short* __restrict__ WbigT){
  long e = ((long)blockIdx.x * 256 + threadIdx.x) << 2;
  if (e < 4194304) {              // U-region: 8192*512
    int n = (int)(e >> 9), kk2 = (int)(e & 511);
    int j = (n >> 9) + 1, dcol = n & 511;
    int i = (kk2 >> 5) + 1, uu = kk2 & 31;
    ushort4 h = {0, 0, 0, 0};
    if (i <= j) h = *(const ushort4*)&G[(long)(j - i) * 16384 + dcol * 32 + uu];
    *(ushort4*)&WbigT[(long)n * 1024 + 512 + kk2] = h;
  } else {                          // Y-region: 1024*1024
    int id2 = (int)(e - 4194304);
    int np = id2 >> 10, kp = id2 & 1023;
    int jm1 = np >> 6, o = np & 63;
    ushort4 h;
    if (kp < 512) {
      h = *(const ushort4*)&CA[(long)(jm1 + 1) * 32768 + o * 512 + kp];
    } else {
      int i = ((kp - 512) >> 5) + 1, u = kp & 31;
      float f0 = 0.f, f1 = 0.f, f2 = 0.f, f3 = 0.f;
      if (i <= jm1 + 1) {
        ushort4 g = *(const ushort4*)&CG[(long)(jm1 + 1 - i) * 2048 + o * 32 + u];
        f0 = bf2f(g.x); f1 = bf2f(g.y); f2 = bf2f(g.z); f3 = bf2f(g.w);
      }
      if (i == jm1 + 1 && o < 50) {
        float s = dtp[0];
        f0 += s * Din[o * 32 + u];     f1 += s * Din[o * 32 + u + 1];
        f2 += s * Din[o * 32 + u + 2]; f3 += s * Din[o * 32 + u + 3];
      }
      h.x = f2bf(f0); h.y = f2bf(f1); h.z = f2bf(f2); h.w = f2bf(f3);
    }
    *(ushort4*)&WbigT[(long)(8192 + np) * 1024 + kp] = h;
  }
}

// pack Xbuf: [Z0 bf16 (c=0 only) | U bf16 for all chunks], 4-wide
__global__ __launch_bounds__(256) void k_packX(
    const float* __restrict__ zdyn, const float* __restrict__ U,
    unsigned short* __restrict__ Xbuf){
  long id4 = (long)blockIdx.x * 256 + threadIdx.x;
  if (id4 < 1048576) {            // U region: 16 c x 512 b x 512 kk2, /4
    long e = id4 << 2;
    long c = e >> 18; int rem = (int)(e & 262143);
    int bb = rem >> 9, kk2 = rem & 511;
    int t = (int)(c * 16) + (kk2 >> 5), uu = kk2 & 31;
    float4 v = *(const float4*)&U[((long)t * 512 + bb) * 32 + uu];
    ushort4 h; h.x = f2bf(v.x); h.y = f2bf(v.y); h.z = f2bf(v.z); h.w = f2bf(v.w);
    *(ushort4*)&Xbuf[c * 524288 + (long)bb * 1024 + 512 + kk2] = h;
  } else {
    long e = (id4 - 1048576) << 2;
    if (e < 262144) {
      int bb = (int)(e >> 9), col = (int)(e & 511);
      float4 v = *(const float4*)&zdyn[(long)bb * 512 + col];
      ushort4 h; h.x = f2bf(v.x); h.y = f2bf(v.y); h.z = f2bf(v.z); h.w = f2bf(v.w);
      *(ushort4*)&Xbuf[(long)bb * 1024 + col] = h;
    }
  }
}

// ---------------------------------------------------------------------------
// Hillis-Steele prefix round (bf16 state): out[c] = in[c] + in[c-h]@R^T
// (pass-through for c<h).  64x64 tiles, dbuf+swizzle+counted vmcnt.
// ---------------------------------------------------------------------------
__global__ __launch_bounds__(256) void k_scanround(
    const unsigned short* __restrict__ Sin, int ldS, long sS,
    const unsigned short* __restrict__ R, int ldR,
    unsigned short* __restrict__ Out, int ldO, long sO, int h){
  __shared__ __align__(16) unsigned short As[2][64 * 64];
  __shared__ __align__(16) unsigned short Bs[2][64 * 64];
  int tid = threadIdx.x, wave = tid >> 6, lane = tid & 63;
  int wm = wave & 1, wn = wave >> 1;
  int c = blockIdx.z;
  int m0 = blockIdx.y * 64, n0 = blockIdx.x * 64;
  int lr = lane & 15, kq = lane >> 4;
  f32x4 acc[2][2];
  f32x4 z4 = {0.f, 0.f, 0.f, 0.f};
  for (int i = 0; i < 2; i++) for (int j = 0; j < 2; j++) acc[i][j] = z4;
  if (c >= h) {
    const unsigned short* Ab = Sin + (long)(c - h) * sS;
    auto stage = [&](int buf, int kt){
      #pragma unroll
      for (int i = 0; i < 2; i++) {
        int base = i * 256 + wave * 64;
        int cc = base + lane; int rr = cc >> 3, sl = cc & 7;
        gll16(Ab + (long)(m0 + rr) * ldS + kt + ((sl ^ (rr & 7)) << 3), &As[buf][base * 8]);
      }
      #pragma unroll
      for (int i = 0; i < 2; i++) {
        int base = i * 256 + wave * 64;
        int cc = base + lane; int rr = cc >> 3, sl = cc & 7;
        gll16(R + (long)(n0 + rr) * ldR + kt + ((sl ^ (rr & 7)) << 3), &Bs[buf][base * 8]);
      }
    };
    stage(0, 0);
    int cur = 0;
    for (int kt = 0; kt < 512; kt += 64) {
      if (kt + 64 < 512) {
        stage(cur ^ 1, kt + 64);
        asm volatile("s_waitcnt vmcnt(4)" ::: "memory");
      } else {
        asm volatile("s_waitcnt vmcnt(0)" ::: "memory");
      }
      __builtin_amdgcn_s_barrier();
      __builtin_amdgcn_sched_barrier(0);
      #pragma unroll
      for (int h2 = 0; h2 < 2; h2++) {
        int eo = (h2 * 32 + kq * 8) ^ ((lr & 7) << 3);
        bf16x8 af[2], bfr[2];
        #pragma unroll
        for (int i = 0; i < 2; i++)
          af[i] = *(const bf16x8*)&As[cur][(wm * 32 + i * 16 + lr) * 64 + eo];
        #pragma unroll
        for (int j = 0; j < 2; j++)
          bfr[j] = *(const bf16x8*)&Bs[cur][(wn * 32 + j * 16 + lr) * 64 + eo];
        #pragma unroll
        for (int i = 0; i < 2; i++)
          #pragma unroll
          for (int j = 0; j < 2; j++)
            acc[i][j] = __builtin_amdgcn_mfma_f32_16x16x32_bf16(af[i], bfr[j], acc[i][j], 0, 0, 0);
      }
      __builtin_amdgcn_s_barrier();
      cur ^= 1;
    }
  }
  const unsigned short* inC = Sin + (long)c * sS;
  unsigned short* OB = Out + (long)c * sO;
  for (int j = 0; j < 2; j++) {
    int n = n0 + wn * 32 + j * 16 + lr;
    for (int i = 0; i < 2; i++)
      for (int r = 0; r < 4; r++) {
        int m = m0 + wm * 32 + i * 16 + kq * 4 + r;
        float v = acc[i][j][r] + bf2f(inC[(long)m * ldS + n]);
        OB[(long)m * ldO + n] = f2bf(v);
      }
  }
}

// ---------------------------------------------------------------------------
// big fused GEMM: all 16 chunks, [z0_c|U_c](512x1024) @ W^T(1024x9216)
//  n<8192 -> Z f32; n>=8192 -> Y f32 (o<50).
//  512 threads / 8 waves (2Mx4N), 128x128 tile, BK=64, dbuf+swizzle+vmcnt.
// ---------------------------------------------------------------------------
__global__ __launch_bounds__(512, 4) void k_mmbig(
    const unsigned short* __restrict__ Xall, const unsigned short* __restrict__ W,
    float* __restrict__ Zout, float* __restrict__ Yout){
  __shared__ __align__(16) unsigned short As[2][128 * 64];
  __shared__ __align__(16) unsigned short Bs[2][128 * 64];
  int tid = threadIdx.x, wave = tid >> 6, lane = tid & 63;
  int wm = wave & 1, wn = wave >> 1;      // 2 M-halves x 4 N-quarters
  int c = blockIdx.z;
  const unsigned short* Xc = Xall + (long)c * 524288;
  int m0 = blockIdx.y * 128, n0 = blockIdx.x * 128;
  int lr = lane & 15, kq = lane >> 4;
  f32x4 acc[4][2];
  f32x4 z4 = {0.f, 0.f, 0.f, 0.f};
  for (int i = 0; i < 4; i++) for (int j = 0; j < 2; j++) acc[i][j] = z4;
  auto stage = [&](int buf, int kt){
    #pragma unroll
    for (int i = 0; i < 2; i++) {
      int cc = i * 512 + tid;            // 1024 chunks of 16B
      int rr = cc >> 3, sl = cc & 7;
      gll16(Xc + (long)(m0 + rr) * 1024 + kt + ((sl ^ (rr & 7)) << 3), &As[buf][cc * 8]);
    }
    #pragma unroll
    for (int i = 0; i < 2; i++) {
      int cc = i * 512 + tid;
      int rr = cc >> 3, sl = cc & 7;
      gll16(W + (long)(n0 + rr) * 1024 + kt + ((sl ^ (rr & 7)) << 3), &Bs[buf][cc * 8]);
    }
  };
  stage(0, 0);
  int cur = 0;
  for (int kt = 0; kt < 1024; kt += 64) {
    if (kt + 64 < 1024) {
      stage(cur ^ 1, kt + 64);
      asm volatile("s_waitcnt vmcnt(4)" ::: "memory");
    } else {
      asm volatile("s_waitcnt vmcnt(0)" ::: "memory");
    }
    __builtin_amdgcn_s_barrier();
    __builtin_amdgcn_sched_barrier(0);
    #pragma unroll
    for (int h = 0; h < 2; h++) {
      int eo = (h * 32 + kq * 8) ^ ((lr & 7) << 3);
      bf16x8 af[4], bfr[2];
      #pragma unroll
      for (int i = 0; i < 4; i++)
        af[i] = *(const bf16x8*)&As[cur][(wm * 64 + i * 16 + lr) * 64 + eo];
      #pragma unroll
      for (int j = 0; j < 2; j++)
        bfr[j] = *(const bf16x8*)&Bs[cur][(wn * 32 + j * 16 + lr) * 64 + eo];
      #pragma unroll
      for (int i = 0; i < 4; i++)
        #pragma unroll
        for (int j = 0; j < 2; j++)
          acc[i][j] = __builtin_amdgcn_mfma_f32_16x16x32_bf16(af[i], bfr[j], acc[i][j], 0, 0, 0);
    }
    __builtin_amdgcn_s_barrier();
    cur ^= 1;
  }
  int t0 = c * 16;
  if (n0 < 8192) {
    int jm1 = n0 >> 9;              // 128-block never crosses a 512 boundary
    float* Zt = Zout + (long)(t0 + jm1) * 262144;
    for (int j = 0; j < 2; j++) {
      int n = n0 + wn * 32 + j * 16 + lr, dcol = n & 511;
      for (int i = 0; i < 4; i++)
        for (int r = 0; r < 4; r++) {
          int m = m0 + wm * 64 + i * 16 + kq * 4 + r;
          Zt[(long)m * 512 + dcol] = acc[i][j][r];
        }
    }
  } else {
    for (int j = 0; j < 2; j++) {
      int n = n0 + wn * 32 + j * 16 + lr;
      int q = n - 8192, jm1 = q >> 6, o = q & 63;
      if (o >= 50) continue;
      int t = t0 + jm1;
      for (int i = 0; i < 4; i++)
        for (int r = 0; r < 4; r++) {
          int m = m0 + wm * 64 + i * 16 + kq * 4 + r;
          Yout[((long)t * 512 + m) * 50 + o] = acc[i][j][r];
        }
    }
  }
}

// ---------------------------------------------------------------------------
// workspace layout (bytes)
// ---------------------------------------------------------------------------
static constexpr long NE2F = 331776L * 4;   // 576^2 f32      = 1,327,104
static constexpr long SPLT = 995328L * 2;   // 576*1728 bf16  = 1,990,656
// region A (expm scratch; only FF is read after the expm chain)
static constexpr long OFF_XF   = 0;
static constexpr long OFF_X2F  = OFF_XF   + NE2F;
static constexpr long OFF_X3F  = OFF_X2F  + NE2F;
static constexpr long OFF_B0F  = OFF_X3F  + NE2F;
static constexpr long OFF_XAP  = OFF_B0F  + NE2F;
static constexpr long OFF_XBT  = OFF_XAP  + SPLT;
static constexpr long OFF_X2AP = OFF_XBT  + SPLT;
static constexpr long OFF_X2BT = OFF_X2AP + SPLT;
static constexpr long OFF_X4BT = OFF_X2BT + SPLT;
static constexpr long OFF_B1AP = OFF_X4BT + SPLT;
static constexpr long OFF_EAP  = OFF_B1AP + SPLT;
static constexpr long OFF_EBT  = OFF_EAP  + SPLT;
static constexpr long OFF_FAP  = OFF_EBT  + SPLT;
static constexpr long OFF_FBT  = OFF_FAP  + SPLT;
static constexpr long OFF_FF   = OFF_FBT  + SPLT;     // 25.21M .. 26.54M
// region B aliases region A (all region-A buffers dead when overwritten)
static constexpr long OFF_WBT  = 0;                            // 9216x1024 bf16
static constexpr long OFF_PT   = 18874368;                     // 16 x 512x512 bf16 = 8 MB
static constexpr long OFF_BBT  = OFF_PT  + 16L * 262144 * 2;   // 27,262,976
static constexpr long OFF_G    = OFF_BBT + 32768;              // (16 x 512x32)
static constexpr long OFF_CA   = OFF_G   + 16L * 16384 * 2;    // (17 x 64x512)
static constexpr long OFF_CG   = OFF_CA  + 17L * 32768 * 2;    // (16 x 64x32)
// Xb overwrites PT/BbarT/G/CA/CG (all dead by k_packX time); ends 35,651,584
static constexpr long OFF_XB   = OFF_PT;

extern "C" void kernel_launch(void* const* d_in, const int* in_sizes, int n_in,
                              void* d_out, int out_size, void* d_ws, size_t ws_size,
                              hipStream_t stream){
  const float* z_dyn = (const float*)d_in[0];
  const float* dtp   = (const float*)d_in[2];
  const float* U     = (const float*)d_in[3];
  const float* skew  = (const float*)d_in[4];
  const float* gamma = (const float*)d_in[5];
  const float* B_ct  = (const float*)d_in[6];
  const float* Cin   = (const float*)d_in[7];
  const float* Din   = (const float*)d_in[8];
  float* Zout = (float*)d_out;
  float* Yout = Zout + 67108864L;   // 256*512*512

  char* ws = (char*)d_ws;
  float* Xf  = (float*)(ws + OFF_XF);
  float* X2f = (float*)(ws + OFF_X2F);
  float* X3f = (float*)(ws + OFF_X3F);
  float* B0f = (float*)(ws + OFF_B0F);
  float* Ff  = (float*)(ws + OFF_FF);
  unsigned short* XAp  = (unsigned short*)(ws + OFF_XAP);
  unsigned short* XBt  = (unsigned short*)(ws + OFF_XBT);
  unsigned short* X2Ap = (unsigned short*)(ws + OFF_X2AP);
  unsigned short* X2Bt = (unsigned short*)(ws + OFF_X2BT);
  unsigned short* X4Bt = (unsigned short*)(ws + OFF_X4BT);
  unsigned short* B1Ap = (unsigned short*)(ws + OFF_B1AP);
  unsigned short* EAp  = (unsigned short*)(ws + OFF_EAP);
  unsigned short* EBt  = (unsigned short*)(ws + OFF_EBT);
  unsigned short* FAp  = (unsigned short*)(ws + OFF_FAP);
  unsigned short* FBt  = (unsigned short*)(ws + OFF_FBT);
  unsigned short* WbigT = (unsigned short*)(ws + OFF_WBT);
  unsigned short* PT    = (unsigned short*)(ws + OFF_PT);
  unsigned short* BbarT = (unsigned short*)(ws + OFF_BBT);
  unsigned short* Gar   = (unsigned short*)(ws + OFF_G);
  unsigned short* CAb   = (unsigned short*)(ws + OFF_CA);
  unsigned short* CGb   = (unsigned short*)(ws + OFF_CG);
  unsigned short* Xb    = (unsigned short*)(ws + OFF_XB);

  // scratch inside d_out (dead before k_mmbig overwrites all of Z and Y)
  unsigned short* Sb  = (unsigned short*)Yout;   // 16 x 512x512 bf16 (ld512)
  unsigned short* M2b = Sb  + 4194304;           // A^32 row-major (ld512)
  unsigned short* TM2 = M2b + 262144;
  unsigned short* M4b = TM2 + 262144;
  unsigned short* TM4 = M4b + 262144;
  unsigned short* M8b = TM4 + 262144;

  dim3 b256(256);
  dim3 gE(18, 18);
  const long WBLK = 524288;  // 512*1024 elements
  const long PBLK = 262144;  // 512*512 elements
  unsigned short* Wlast = WbigT + 15L * WBLK;

  // ---- expm(Maug*dt): scaling s=2 + degree-7 PS Taylor (6 GEMMs) ----
  k_build_M<<<dim3(324), b256, 0, stream>>>(skew, gamma, dtp, B_ct, Xf, XAp, XBt);
  k_expm_gemm<<<gE, b256, 0, stream>>>(XAp,  XBt,  nullptr, X2f, X2Ap, X2Bt);      // X2
  k_expm_gemm<<<gE, b256, 0, stream>>>(X2Ap, XBt,  nullptr, X3f, nullptr, nullptr); // X3
  k_expm_gemm<<<gE, b256, 0, stream>>>(X2Ap, X2Bt, nullptr, nullptr, nullptr, X4Bt);// X4
  k_poly<<<dim3(1296), b256, 0, stream>>>(Xf, X2f, X3f, B0f, B1Ap);
  k_expm_gemm<<<gE, b256, 0, stream>>>(B1Ap, X4Bt, B0f, nullptr, EAp, EBt);        // E = B1*X4+B0
  k_expm_gemm<<<gE, b256, 0, stream>>>(EAp, EBt, nullptr, nullptr, FAp, FBt);      // F = E^2
  k_expm_gemm<<<gE, b256, 0, stream>>>(FAp, FBt, nullptr, Ff, nullptr, nullptr);   // Ff = F^2

  // ---- extract A_bar/B_bar, padded C ----
  k_extract<<<dim3(260), b256, 0, stream>>>(Ff, Cin, WbigT, PT, BbarT, Gar, CAb);

  // ---- powers of A by doubling (transpose fused via outT -> PT blocks) ----
  k_btgemm<64,64,2,2><<<dim3(8,8,1), b256, 0, stream>>>(WbigT, 1024, 0, PT, 512, 0, WbigT + WBLK, 1024, 0, 512, PT + PBLK, 512, 0);                    // A2 (+PT2)
  k_btgemm<64,64,2,2><<<dim3(8,8,2), b256, 0, stream>>>(WbigT + WBLK, 1024, 0, PT, 512, PBLK, WbigT + 2*WBLK, 1024, WBLK, 512, PT + 2*PBLK, 512, PBLK); // A3,4 (+PT3,4)
  k_btgemm<64,64,2,2><<<dim3(8,8,4), b256, 0, stream>>>(WbigT + 3*WBLK, 1024, 0, PT, 512, PBLK, WbigT + 4*WBLK, 1024, WBLK, 512, PT + 4*PBLK, 512, PBLK);// A5..8 (+PT5..8)
  k_btgemm<64,64,2,2><<<dim3(8,8,8), b256, 0, stream>>>(WbigT + 7*WBLK, 1024, 0, PT, 512, PBLK, WbigT + 8*WBLK, 1024, WBLK, 512, PT + 8*PBLK, 512, PBLK);// A9..16 (+PT9..16)

  // ---- prefix-scan powers A^32/A^64/A^128 (before packX overwrites PT) ----
  k_btgemm<64,64,2,2><<<dim3(8,8,1), b256, 0, stream>>>(Wlast, 1024, 0, PT + 15*PBLK, 512, 0, M2b, 512, 0, 512, TM2, 512, 0);
  k_btgemm<64,64,2,2><<<dim3(8,8,1), b256, 0, stream>>>(M2b, 512, 0, TM2, 512, 0, M4b, 512, 0, 512, TM4, 512, 0);
  k_btgemm<64,64,2,2><<<dim3(8,8,1), b256, 0, stream>>>(M4b, 512, 0, TM4, 512, 0, M8b, 512, 0, 512, nullptr, 0, 0);

  // ---- G_k = A^k * B_bar (k=1..15); CA_m = C@A^m; CG_m = CA_m@B_bar ----
  k_btgemm<64,32,4,1><<<dim3(1,8,15), b256, 0, stream>>>(WbigT, 1024, WBLK, BbarT, 512, 0, Gar + 16384, 32, 16384, 512, nullptr, 0, 0);
  k_btgemm<64,64,2,2><<<dim3(8,1,8), b256, 0, stream>>>(CAb, 512, 0, PT, 512, PBLK, CAb + 32768, 512, 32768, 512, nullptr, 0, 0);                    // CA1..8
  k_btgemm<64,64,2,2><<<dim3(8,1,8), b256, 0, stream>>>(CAb + 32768, 512, 32768, PT + 7*PBLK, 512, 0, CAb + 9L*32768, 512, 32768, 512, nullptr, 0, 0); // CA9..16
  k_btgemm<64,32,4,1><<<dim3(1,1,16), b256, 0, stream>>>(CAb, 512, 32768, BbarT, 512, 0, CGb, 32, 2048, 512, nullptr, 0, 0);                         // CG0..15

  // ---- assemble W (U+Y regions), pack X (overwrites PT..CG with Xb) ----
  k_assembleUW<<<dim3(5120), b256, 0, stream>>>(Gar, CAb, CGb, Din, dtp, WbigT);
  k_packX<<<dim3(4353), b256, 0, stream>>>(z_dyn, U, Xb);

  // ---- Ubar_c = U_c @ GU^T -> init S[c+1] (bf16 into Xb z0-slots) ----
  k_btgemm<64,64,2,2><<<dim3(8,8,15), b256, 0, stream>>>(
      Xb + 512, 1024, WBLK, Wlast + 512, 1024, 0,
      Xb + WBLK, 1024, WBLK, 512, nullptr, 0, 0);

  // ---- Hillis-Steele: 4 rounds, bf16 ping-pong ----
  k_scanround<<<dim3(8,8,16), b256, 0, stream>>>(Xb, 1024, WBLK, Wlast, 1024, Sb, 512, PBLK, 1);
  k_scanround<<<dim3(8,8,16), b256, 0, stream>>>(Sb, 512, PBLK, M2b, 512, Xb, 1024, WBLK, 2);
  k_scanround<<<dim3(8,8,16), b256, 0, stream>>>(Xb, 1024, WBLK, M4b, 512, Sb, 512, PBLK, 4);
  k_scanround<<<dim3(8,8,16), b256, 0, stream>>>(Sb, 512, PBLK, M8b, 512, Xb, 1024, WBLK, 8);

  // ---- ONE parallel dispatch: all 16 chunks, Z (n<8192) + Y (n>=8192) ----
  k_mmbig<<<dim3(72, 4, 16), dim3(512), 0, stream>>>(Xb, WbigT, Zout, Yout);
}

// Round 5
// 632.667 us; speedup vs baseline: 1.0999x; 1.0999x over previous
//
#include <hip/hip_runtime.h>
#include <stdint.h>

// ---------------------------------------------------------------------------
// ConditionedCTKoopmanTransition: d=512, u=32, n_obs=50, B=512, T=256
// v6:
//   1. k_mmbig K-skip: W's U-region is block-triangular; per n-block
//      kmax = align64(512+32j) (Z) / 576+q/2 (Y). -22% GEMM work, exact.
//   2. Dispatch merges (in-stream kernels serialize; merged = overlapped):
//      X3+X4 batched (z=2); G1..15+CA1..8 one dispatch; CG0..15+packX one
//      dispatch. 27 -> 23 dispatches.
//   3. Layout: BbarT/G/CA/CG moved above Xb alias span (ends 37.39MB,
//      within the 38.4MB footprint proven in round 0).
// ---------------------------------------------------------------------------

typedef __bf16 bf16x8 __attribute__((ext_vector_type(8)));
typedef float  f32x4  __attribute__((ext_vector_type(4)));

#define NE  576
#define NE3 1728   // 3*NE (split-bf16: [hi|hi|lo] x [hi|lo|hi])

__device__ __forceinline__ unsigned short f2bf(float x){
  union { float f; unsigned int u; } v; v.f = x;
  unsigned int r = (v.u + 0x7fffu + ((v.u >> 16) & 1u)) >> 16;
  return (unsigned short)r;
}
__device__ __forceinline__ float bf2f(unsigned short h){
  union { float f; unsigned int u; } v; v.u = ((unsigned int)h) << 16;
  return v.f;
}

__device__ __forceinline__ void gll16(const void* g, void* l){
  __builtin_amdgcn_global_load_lds((__attribute__((address_space(1))) void*)g,
                                   (__attribute__((address_space(3))) void*)l,
                                   16, 0, 0);
}

// ---------------------------------------------------------------------------
// build scaled augmented matrix X = Maug * dt / 4, f32 + split forms.
// ---------------------------------------------------------------------------
__global__ __launch_bounds__(256) void k_build_M(
    const float* __restrict__ skew, const float* __restrict__ gamma,
    const float* __restrict__ dtp, const float* __restrict__ B_ct,
    float* __restrict__ Xf, unsigned short* __restrict__ XAp,
    unsigned short* __restrict__ XBt){
  __shared__ float T[32][33];
  int bx = blockIdx.x % 18, by = blockIdx.x / 18;
  int r0 = by * 32, c0 = bx * 32;
  int tr = threadIdx.x >> 5, tc = threadIdx.x & 31;   // 8 x 32
  float sc = dtp[0] * 0.25f;     // s=2 scaling
  #pragma unroll
  for (int p = 0; p < 4; p++) {
    int r = r0 + p * 8 + tr, c = c0 + tc;
    float v = 0.f;
    if (r < 512 && c < 512) {
      if (r < c) {
        long k = 511L * r - (long)r * (r - 1) / 2 + (c - r - 1);
        v = skew[k];
      } else if (r > c) {
        long k = 511L * c - (long)c * (c - 1) / 2 + (r - c - 1);
        v = -skew[k];
      } else {
        float g = gamma[r];
        float sp = (g > 20.f) ? g : log1pf(expf(g));
        v = -sp;
      }
    } else if (r < 512 && c >= 512 && c < 544) {
      v = B_ct[r * 32 + (c - 512)];
    }
    v *= sc;
    long id = (long)r * NE + c;
    Xf[id] = v;
    unsigned short hi = f2bf(v);
    unsigned short lo = f2bf(v - bf2f(hi));
    XAp[(long)r * NE3 + c]          = hi;
    XAp[(long)r * NE3 + NE + c]     = hi;
    XAp[(long)r * NE3 + 2 * NE + c] = lo;
    T[p * 8 + tr][tc] = v;
  }
  __syncthreads();
  #pragma unroll
  for (int p = 0; p < 4; p++) {
    int cl = p * 8 + tr, rl = tc;
    float v = T[rl][cl];
    unsigned short hi = f2bf(v);
    unsigned short lo = f2bf(v - bf2f(hi));
    long base = (long)(c0 + cl) * NE3 + r0;
    XBt[base + rl]          = hi;
    XBt[base + NE + rl]     = lo;
    XBt[base + 2 * NE + rl] = hi;
  }
}

// ---------------------------------------------------------------------------
// split-bf16 GEMM for expm, K=1728, BK=192, dbuf+swizzle+counted vmcnt.
// Dual-parameter: blockIdx.z==1 uses the second set (batch 2 indep GEMMs).
// ---------------------------------------------------------------------------
__global__ __launch_bounds__(256) void k_expm_gemm(
    const unsigned short* __restrict__ Ap0, const unsigned short* __restrict__ Bt0,
    const float* __restrict__ Cadd0, float* __restrict__ outF0,
    unsigned short* __restrict__ outAp0, unsigned short* __restrict__ outBt0,
    const unsigned short* __restrict__ Ap1, const unsigned short* __restrict__ Bt1,
    const float* __restrict__ Cadd1, float* __restrict__ outF1,
    unsigned short* __restrict__ outAp1, unsigned short* __restrict__ outBt1){
  const unsigned short* Ap = Ap0;  const unsigned short* Bt = Bt0;
  const float* Cadd = Cadd0;       float* outF = outF0;
  unsigned short* outAp = outAp0;  unsigned short* outBt = outBt0;
  if (blockIdx.z) {
    Ap = Ap1; Bt = Bt1; Cadd = Cadd1; outF = outF1; outAp = outAp1; outBt = outBt1;
  }
  __shared__ __align__(16) unsigned short As[2][32 * 192];
  __shared__ __align__(16) unsigned short Bs[2][32 * 192];
  int tid = threadIdx.x, wave = tid >> 6, lane = tid & 63;
  int wm = wave & 1, wn = wave >> 1;
  int m0 = blockIdx.y * 32, n0 = blockIdx.x * 32;
  int lr = lane & 15, kq = lane >> 4;
  f32x4 acc = {0.f, 0.f, 0.f, 0.f};
  auto stage = [&](int buf, int kt){
    #pragma unroll
    for (int i = 0; i < 3; i++) {
      int base = i * 256 + wave * 64;     // wave-uniform LDS base
      int cc = base + lane;
      int rr = cc / 24, sl = cc - rr * 24;
      int ss = (sl & 24) | ((sl & 7) ^ (rr & 7));
      gll16(Ap + (long)(m0 + rr) * NE3 + kt + ss * 8, &As[buf][base * 8]);
      gll16(Bt + (long)(n0 + rr) * NE3 + kt + ss * 8, &Bs[buf][base * 8]);
    }
  };
  stage(0, 0);
  int cur = 0;
  for (int kt = 0; kt < NE3; kt += 192) {
    if (kt + 192 < NE3) {
      stage(cur ^ 1, kt + 192);
      asm volatile("s_waitcnt vmcnt(6)" ::: "memory");
    } else {
      asm volatile("s_waitcnt vmcnt(0)" ::: "memory");
    }
    __builtin_amdgcn_s_barrier();
    __builtin_amdgcn_sched_barrier(0);
    #pragma unroll
    for (int hh = 0; hh < 6; hh++) {
      int eo = (hh * 32 + kq * 8) ^ ((lr & 7) << 3);
      bf16x8 af = *(const bf16x8*)&As[cur][(wm * 16 + lr) * 192 + eo];
      bf16x8 bf = *(const bf16x8*)&Bs[cur][(wn * 16 + lr) * 192 + eo];
      acc = __builtin_amdgcn_mfma_f32_16x16x32_bf16(af, bf, acc, 0, 0, 0);
    }
    __builtin_amdgcn_s_barrier();
    cur ^= 1;
  }
  int n = n0 + wn * 16 + lr;
  for (int i = 0; i < 4; i++) {
    int m = m0 + wm * 16 + kq * 4 + i;
    float v = acc[i];
    if (Cadd) v += Cadd[(long)m * NE + n];
    if (outF) outF[(long)m * NE + n] = v;
    unsigned short hi = f2bf(v);
    unsigned short lo = f2bf(v - bf2f(hi));
    if (outAp) {
      outAp[(long)m * NE3 + n]          = hi;
      outAp[(long)m * NE3 + NE + n]     = hi;
      outAp[(long)m * NE3 + 2 * NE + n] = lo;
    }
    if (outBt) {
      outBt[(long)n * NE3 + m]          = hi;
      outBt[(long)n * NE3 + NE + m]     = lo;
      outBt[(long)n * NE3 + 2 * NE + m] = hi;
    }
  }
}

// ---------------------------------------------------------------------------
// degree-7 PS coefficients: B0 (f32 Cadd), B1 (split Ap).  E = B1*X4 + B0
// ---------------------------------------------------------------------------
__global__ __launch_bounds__(256) void k_poly(
    const float* __restrict__ Xf, const float* __restrict__ X2f,
    const float* __restrict__ X3f, float* __restrict__ B0,
    unsigned short* __restrict__ B1Ap){
  int id = blockIdx.x * 256 + threadIdx.x;
  if (id >= NE * NE) return;
  int r = id / NE, c = id % NE;
  float x = Xf[id], x2 = X2f[id], x3 = X3f[id];
  float ii = (r == c) ? 1.f : 0.f;
  float b0 = ii + x + x2 * 0.5f + x3 * (1.f / 6.f);
  float b1 = ii * (1.f / 24.f) + x * (1.f / 120.f) + x2 * (1.f / 720.f) + x3 * (1.f / 5040.f);
  B0[id] = b0;
  unsigned short hi = f2bf(b1), lo = f2bf(b1 - bf2f(hi));
  B1Ap[(long)r * NE3 + c]          = hi;
  B1Ap[(long)r * NE3 + NE + c]     = hi;
  B1Ap[(long)r * NE3 + 2 * NE + c] = lo;
}

// ---------------------------------------------------------------------------
// extract A_bar/B_bar from expm result; padded C (64 rows) as CA block 0.
// ---------------------------------------------------------------------------
__global__ __launch_bounds__(256) void k_extract(
    const float* __restrict__ F, const float* __restrict__ Cin,
    unsigned short* __restrict__ WbigT, unsigned short* __restrict__ PT1,
    unsigned short* __restrict__ BbarT, unsigned short* __restrict__ G0,
    unsigned short* __restrict__ CA0){
  int b = blockIdx.x;
  if (b < 256) {
    __shared__ float T[32][33];
    int by = b >> 4, bx = b & 15;
    int m0 = by * 32, k0 = bx * 32;
    int tr = threadIdx.x >> 5, tc = threadIdx.x & 31;
    #pragma unroll
    for (int p = 0; p < 4; p++) {
      int m = m0 + p * 8 + tr, k = k0 + tc;
      float v = F[(long)m * NE + k];
      WbigT[(long)m * 1024 + k] = f2bf(v);
      T[p * 8 + tr][tc] = v;
    }
    __syncthreads();
    #pragma unroll
    for (int p = 0; p < 4; p++) {
      int kl = p * 8 + tr, ml = tc;
      PT1[(long)(k0 + kl) * 512 + m0 + ml] = f2bf(T[ml][kl]);
    }
  } else {
    int id0 = (b - 256) * 256 + threadIdx.x;
    for (int id = id0; id < 64 * 512; id += 1024) {
      if (id < 512 * 32) {
        int dd = id >> 5, u = id & 31;
        unsigned short h = f2bf(F[(long)dd * NE + 512 + u]);
        G0[id] = h;                         // B_bar row-major (512x32)
        BbarT[(long)u * 512 + dd] = h;      // B_bar^T (32x512)
      }
      CA0[id] = (id < 50 * 512) ? f2bf(Cin[id]) : (unsigned short)0;
    }
  }
}

// ---------------------------------------------------------------------------
// generic bf16 "bt" GEMM, BK=64, dbuf+swizzle+counted vmcnt:
//   C[m,n] = sum_k A[m,k]*Bt[n,k]; optional transpose output outT = C^T.
// ---------------------------------------------------------------------------
template<int BM, int BN, int WM, int WN>
__global__ __launch_bounds__(256) void k_btgemm(
    const unsigned short* __restrict__ A, int ldA, long sAz,
    const unsigned short* __restrict__ Bt, int ldB, long sBz,
    unsigned short* __restrict__ C, int ldC, long sCz, int K,
    unsigned short* __restrict__ outT, int ldT, long sTz){
  constexpr int FM = BM / (16 * WM), FN = BN / (16 * WN);
  constexpr int LA = BM / 32, LB = BN / 32;
  __shared__ __align__(16) unsigned short As[2][BM * 64];
  __shared__ __align__(16) unsigned short Bs[2][BN * 64];
  int tid = threadIdx.x, wave = tid >> 6, lane = tid & 63;
  int wm = wave % WM, wn = wave / WM;
  long z = blockIdx.z;
  const unsigned short* Ab = A + z * sAz;
  const unsigned short* Bb = Bt + z * sBz;
  int m0 = blockIdx.y * BM, n0 = blockIdx.x * BN;
  int lr = lane & 15, kq = lane >> 4;
  f32x4 acc[FM][FN];
  f32x4 z4 = {0.f, 0.f, 0.f, 0.f};
  for (int i = 0; i < FM; i++) for (int j = 0; j < FN; j++) acc[i][j] = z4;
  auto stage = [&](int buf, int kt){
    #pragma unroll
    for (int i = 0; i < LA; i++) {
      int base = i * 256 + wave * 64;
      int cc = base + lane; int rr = cc >> 3, sl = cc & 7;
      gll16(Ab + (long)(m0 + rr) * ldA + kt + ((sl ^ (rr & 7)) << 3), &As[buf][base * 8]);
    }
    #pragma unroll
    for (int i = 0; i < LB; i++) {
      int base = i * 256 + wave * 64;
      int cc = base + lane; int rr = cc >> 3, sl = cc & 7;
      gll16(Bb + (long)(n0 + rr) * ldB + kt + ((sl ^ (rr & 7)) << 3), &Bs[buf][base * 8]);
    }
  };
  stage(0, 0);
  int cur = 0;
  for (int kt = 0; kt < K; kt += 64) {
    if (kt + 64 < K) {
      stage(cur ^ 1, kt + 64);
      asm volatile("s_waitcnt vmcnt(%0)" :: "i"(LA + LB) : "memory");
    } else {
      asm volatile("s_waitcnt vmcnt(0)" ::: "memory");
    }
    __builtin_amdgcn_s_barrier();
    __builtin_amdgcn_sched_barrier(0);
    #pragma unroll
    for (int h = 0; h < 2; h++) {
      int eo = (h * 32 + kq * 8) ^ ((lr & 7) << 3);
      bf16x8 af[FM], bfr[FN];
      #pragma unroll
      for (int i = 0; i < FM; i++)
        af[i] = *(const bf16x8*)&As[cur][(wm * (16 * FM) + i * 16 + lr) * 64 + eo];
      #pragma unroll
      for (int j = 0; j < FN; j++)
        bfr[j] = *(const bf16x8*)&Bs[cur][(wn * (16 * FN) + j * 16 + lr) * 64 + eo];
      #pragma unroll
      for (int i = 0; i < FM; i++)
        #pragma unroll
        for (int j = 0; j < FN; j++)
          acc[i][j] = __builtin_amdgcn_mfma_f32_16x16x32_bf16(af[i], bfr[j], acc[i][j], 0, 0, 0);
    }
    __builtin_amdgcn_s_barrier();
    cur ^= 1;
  }
  unsigned short* Cb = C + z * sCz;
  unsigned short* Tb = outT ? outT + z * sTz : nullptr;
  for (int i = 0; i < FM; i++)
    for (int j = 0; j < FN; j++) {
      int n = n0 + wn * (16 * FN) + j * 16 + lr;
      for (int r = 0; r < 4; r++) {
        int m = m0 + wm * (16 * FM) + i * 16 + kq * 4 + r;
        unsigned short hv = f2bf(acc[i][j][r]);
        Cb[(long)m * ldC + n] = hv;
        if (Tb) Tb[(long)n * ldT + m] = hv;
      }
    }
}

// ---------------------------------------------------------------------------
// shared 64x32-tile GEMM body (BM=64,BN=32, 4 waves, K=512, dbuf+swizzle)
// As: 2 bufs x 64*64 shorts; Bs: 2 bufs x 32*64 shorts.
// ---------------------------------------------------------------------------
__device__ __forceinline__ void gemm6432(
    const unsigned short* __restrict__ Ab, int ldA,
    const unsigned short* __restrict__ Bb, int ldB,
    unsigned short* __restrict__ Cb, int ldC, int m0, int n0,
    unsigned short* As, unsigned short* Bs){
  int tid = threadIdx.x, wave = tid >> 6, lane = tid & 63;
  int wm = wave & 3;
  int lr = lane & 15, kq = lane >> 4;
  f32x4 acc[2];
  f32x4 z4 = {0.f, 0.f, 0.f, 0.f};
  acc[0] = z4; acc[1] = z4;
  auto stage = [&](int buf, int kt){
    #pragma unroll
    for (int i = 0; i < 2; i++) {
      int cc = i * 256 + tid; int rr = cc >> 3, sl = cc & 7;
      gll16(Ab + (long)(m0 + rr) * ldA + kt + ((sl ^ (rr & 7)) << 3), As + buf * 4096 + cc * 8);
    }
    {
      int cc = tid; int rr = cc >> 3, sl = cc & 7;
      gll16(Bb + (long)(n0 + rr) * ldB + kt + ((sl ^ (rr & 7)) << 3), Bs + buf * 2048 + cc * 8);
    }
  };
  stage(0, 0);
  int cur = 0;
  for (int kt = 0; kt < 512; kt += 64) {
    if (kt + 64 < 512) {
      stage(cur ^ 1, kt + 64);
      asm volatile("s_waitcnt vmcnt(3)" ::: "memory");
    } else {
      asm volatile("s_waitcnt vmcnt(0)" ::: "memory");
    }
    __builtin_amdgcn_s_barrier();
    __builtin_amdgcn_sched_barrier(0);
    #pragma unroll
    for (int h = 0; h < 2; h++) {
      int eo = (h * 32 + kq * 8) ^ ((lr & 7) << 3);
      bf16x8 af = *(const bf16x8*)&As[cur * 4096 + (wm * 16 + lr) * 64 + eo];
      #pragma unroll
      for (int j = 0; j < 2; j++) {
        bf16x8 bfv = *(const bf16x8*)&Bs[cur * 2048 + (j * 16 + lr) * 64 + eo];
        acc[j] = __builtin_amdgcn_mfma_f32_16x16x32_bf16(af, bfv, acc[j], 0, 0, 0);
      }
    }
    __builtin_amdgcn_s_barrier();
    cur ^= 1;
  }
  for (int j = 0; j < 2; j++) {
    int n = n0 + j * 16 + lr;
    for (int r = 0; r < 4; r++) {
      int m = m0 + wm * 16 + kq * 4 + r;
      Cb[(long)m * ldC + n] = f2bf(acc[j][r]);
    }
  }
}

// merged dispatch: z<15 -> G_{z+1} = A^{z+1} @ B_bar; z>=15 -> CA_{z-14} = C @ A^{z-14}
__global__ __launch_bounds__(256) void k_gca(
    const unsigned short* __restrict__ Wbig, const unsigned short* __restrict__ BbarT,
    const unsigned short* __restrict__ CAb, const unsigned short* __restrict__ PT,
    unsigned short* __restrict__ G1, unsigned short* __restrict__ CAout){
  __shared__ __align__(16) unsigned short As[2 * 64 * 64];
  __shared__ __align__(16) unsigned short Bs[2 * 32 * 64];
  int z = blockIdx.z;
  if (z < 15) {
    if (blockIdx.x) return;
    gemm6432(Wbig + (long)z * 524288, 1024, BbarT, 512,
             G1 + (long)z * 16384, 32, blockIdx.y * 64, 0, As, Bs);
  } else {
    if (blockIdx.y) return;
    int zz = z - 15;
    gemm6432(CAb, 512, PT + (long)zz * 262144, 512,
             CAout + (long)zz * 32768, 512, 0, blockIdx.x * 32, As, Bs);
  }
}

// merged dispatch: blocks 0..15 -> CG_m = CA_m @ B_bar; blocks 16.. -> packX
__global__ __launch_bounds__(256) void k_cgpack(
    const unsigned short* __restrict__ CAb, const unsigned short* __restrict__ BbarT,
    unsigned short* __restrict__ CGb,
    const float* __restrict__ zdyn, const float* __restrict__ Uin,
    unsigned short* __restrict__ Xbuf){
  int b = blockIdx.x;
  if (b < 16) {
    __shared__ __align__(16) unsigned short As[2 * 64 * 64];
    __shared__ __align__(16) unsigned short Bs[2 * 32 * 64];
    gemm6432(CAb + (long)b * 32768, 512, BbarT, 512,
             CGb + (long)b * 2048, 32, 0, 0, As, Bs);
    return;
  }
  long id4 = (long)(b - 16) * 256 + threadIdx.x;
  if (id4 < 1048576) {            // U region: 16 c x 512 b x 512 kk2, /4
    long e = id4 << 2;
    long c = e >> 18; int rem = (int)(e & 262143);
    int bb = rem >> 9, kk2 = rem & 511;
    int t = (int)(c * 16) + (kk2 >> 5), uu = kk2 & 31;
    float4 v = *(const float4*)&Uin[((long)t * 512 + bb) * 32 + uu];
    ushort4 h; h.x = f2bf(v.x); h.y = f2bf(v.y); h.z = f2bf(v.z); h.w = f2bf(v.w);
    *(ushort4*)&Xbuf[c * 524288 + (long)bb * 1024 + 512 + kk2] = h;
  } else {
    long e = (id4 - 1048576) << 2;
    if (e < 262144) {
      int bb = (int)(e >> 9), col = (int)(e & 511);
      float4 v = *(const float4*)&zdyn[(long)bb * 512 + col];
      ushort4 h; h.x = f2bf(v.x); h.y = f2bf(v.y); h.z = f2bf(v.z); h.w = f2bf(v.w);
      *(ushort4*)&Xbuf[(long)bb * 1024 + col] = h;
    }
  }
}

// ---------------------------------------------------------------------------
// merged fill of U-region (rows 0..8191) and Y-region (rows 8192..9215)
// ---------------------------------------------------------------------------
__global__ __launch_bounds__(256) void k_assembleUW(
    const unsigned short* __restrict__ G, const unsigned short* __restrict__ CA,
    const unsigned short* __restrict__ CG, const float* __restrict__ Din,
    const float* __restrict__ dtp, unsigned short* __restrict__ WbigT){
  long e = ((long)blockIdx.x * 256 + threadIdx.x) << 2;
  if (e < 4194304) {              // U-region: 8192*512
    int n = (int)(e >> 9), kk2 = (int)(e & 511);
    int j = (n >> 9) + 1, dcol = n & 511;
    int i = (kk2 >> 5) + 1, uu = kk2 & 31;
    ushort4 h = {0, 0, 0, 0};
    if (i <= j) h = *(const ushort4*)&G[(long)(j - i) * 16384 + dcol * 32 + uu];
    *(ushort4*)&WbigT[(long)n * 1024 + 512 + kk2] = h;
  } else {                          // Y-region: 1024*1024
    int id2 = (int)(e - 4194304);
    int np = id2 >> 10, kp = id2 & 1023;
    int jm1 = np >> 6, o = np & 63;
    ushort4 h;
    if (kp < 512) {
      h = *(const ushort4*)&CA[(long)(jm1 + 1) * 32768 + o * 512 + kp];
    } else {
      int i = ((kp - 512) >> 5) + 1, u = kp & 31;
      float f0 = 0.f, f1 = 0.f, f2 = 0.f, f3 = 0.f;
      if (i <= jm1 + 1) {
        ushort4 g = *(const ushort4*)&CG[(long)(jm1 + 1 - i) * 2048 + o * 32 + u];
        f0 = bf2f(g.x); f1 = bf2f(g.y); f2 = bf2f(g.z); f3 = bf2f(g.w);
      }
      if (i == jm1 + 1 && o < 50) {
        float s = dtp[0];
        f0 += s * Din[o * 32 + u];     f1 += s * Din[o * 32 + u + 1];
        f2 += s * Din[o * 32 + u + 2]; f3 += s * Din[o * 32 + u + 3];
      }
      h.x = f2bf(f0); h.y = f2bf(f1); h.z = f2bf(f2); h.w = f2bf(f3);
    }
    *(ushort4*)&WbigT[(long)(8192 + np) * 1024 + kp] = h;
  }
}

// ---------------------------------------------------------------------------
// Hillis-Steele prefix round (bf16 state): out[c] = in[c] + in[c-h]@R^T
// ---------------------------------------------------------------------------
__global__ __launch_bounds__(256) void k_scanround(
    const unsigned short* __restrict__ Sin, int ldS, long sS,
    const unsigned short* __restrict__ R, int ldR,
    unsigned short* __restrict__ Out, int ldO, long sO, int h){
  __shared__ __align__(16) unsigned short As[2][64 * 64];
  __shared__ __align__(16) unsigned short Bs[2][64 * 64];
  int tid = threadIdx.x, wave = tid >> 6, lane = tid & 63;
  int wm = wave & 1, wn = wave >> 1;
  int c = blockIdx.z;
  int m0 = blockIdx.y * 64, n0 = blockIdx.x * 64;
  int lr = lane & 15, kq = lane >> 4;
  f32x4 acc[2][2];
  f32x4 z4 = {0.f, 0.f, 0.f, 0.f};
  for (int i = 0; i < 2; i++) for (int j = 0; j < 2; j++) acc[i][j] = z4;
  if (c >= h) {
    const unsigned short* Ab = Sin + (long)(c - h) * sS;
    auto stage = [&](int buf, int kt){
      #pragma unroll
      for (int i = 0; i < 2; i++) {
        int base = i * 256 + wave * 64;
        int cc = base + lane; int rr = cc >> 3, sl = cc & 7;
        gll16(Ab + (long)(m0 + rr) * ldS + kt + ((sl ^ (rr & 7)) << 3), &As[buf][base * 8]);
      }
      #pragma unroll
      for (int i = 0; i < 2; i++) {
        int base = i * 256 + wave * 64;
        int cc = base + lane; int rr = cc >> 3, sl = cc & 7;
        gll16(R + (long)(n0 + rr) * ldR + kt + ((sl ^ (rr & 7)) << 3), &Bs[buf][base * 8]);
      }
    };
    stage(0, 0);
    int cur = 0;
    for (int kt = 0; kt < 512; kt += 64) {
      if (kt + 64 < 512) {
        stage(cur ^ 1, kt + 64);
        asm volatile("s_waitcnt vmcnt(4)" ::: "memory");
      } else {
        asm volatile("s_waitcnt vmcnt(0)" ::: "memory");
      }
      __builtin_amdgcn_s_barrier();
      __builtin_amdgcn_sched_barrier(0);
      #pragma unroll
      for (int h2 = 0; h2 < 2; h2++) {
        int eo = (h2 * 32 + kq * 8) ^ ((lr & 7) << 3);
        bf16x8 af[2], bfr[2];
        #pragma unroll
        for (int i = 0; i < 2; i++)
          af[i] = *(const bf16x8*)&As[cur][(wm * 32 + i * 16 + lr) * 64 + eo];
        #pragma unroll
        for (int j = 0; j < 2; j++)
          bfr[j] = *(const bf16x8*)&Bs[cur][(wn * 32 + j * 16 + lr) * 64 + eo];
        #pragma unroll
        for (int i = 0; i < 2; i++)
          #pragma unroll
          for (int j = 0; j < 2; j++)
            acc[i][j] = __builtin_amdgcn_mfma_f32_16x16x32_bf16(af[i], bfr[j], acc[i][j], 0, 0, 0);
      }
      __builtin_amdgcn_s_barrier();
      cur ^= 1;
    }
  }
  const unsigned short* inC = Sin + (long)c * sS;
  unsigned short* OB = Out + (long)c * sO;
  for (int j = 0; j < 2; j++) {
    int n = n0 + wn * 32 + j * 16 + lr;
    for (int i = 0; i < 2; i++)
      for (int r = 0; r < 4; r++) {
        int m = m0 + wm * 32 + i * 16 + kq * 4 + r;
        float v = acc[i][j][r] + bf2f(inC[(long)m * ldS + n]);
        OB[(long)m * ldO + n] = f2bf(v);
      }
  }
}

// ---------------------------------------------------------------------------
// big fused GEMM with block-triangular K-skip:
//  Z-region (n0<8192):  kmax = align64(512 + 32*j), j = n0/512 + 1
//  Y-region (n0>=8192): kmax = 576 + (n0-8192)/2
// ---------------------------------------------------------------------------
__global__ __launch_bounds__(512, 4) void k_mmbig(
    const unsigned short* __restrict__ Xall, const unsigned short* __restrict__ W,
    float* __restrict__ Zout, float* __restrict__ Yout){
  __shared__ __align__(16) unsigned short As[2][128 * 64];
  __shared__ __align__(16) unsigned short Bs[2][128 * 64];
  int tid = threadIdx.x, wave = tid >> 6, lane = tid & 63;
  int wm = wave & 1, wn = wave >> 1;      // 2 M-halves x 4 N-quarters
  int c = blockIdx.z;
  const unsigned short* Xc = Xall + (long)c * 524288;
  int m0 = blockIdx.y * 128, n0 = blockIdx.x * 128;
  int kmax;
  if (n0 < 8192) {
    int j = (n0 >> 9) + 1;
    kmax = (512 + 32 * j + 63) & ~63;
  } else {
    kmax = 576 + ((n0 - 8192) >> 1);
  }
  int lr = lane & 15, kq = lane >> 4;
  f32x4 acc[4][2];
  f32x4 z4 = {0.f, 0.f, 0.f, 0.f};
  for (int i = 0; i < 4; i++) for (int j = 0; j < 2; j++) acc[i][j] = z4;
  auto stage = [&](int buf, int kt){
    #pragma unroll
    for (int i = 0; i < 2; i++) {
      int cc = i * 512 + tid;            // 1024 chunks of 16B
      int rr = cc >> 3, sl = cc & 7;
      gll16(Xc + (long)(m0 + rr) * 1024 + kt + ((sl ^ (rr & 7)) << 3), &As[buf][cc * 8]);
    }
    #pragma unroll
    for (int i = 0; i < 2; i++) {
      int cc = i * 512 + tid;
      int rr = cc >> 3, sl = cc & 7;
      gll16(W + (long)(n0 + rr) * 1024 + kt + ((sl ^ (rr & 7)) << 3), &Bs[buf][cc * 8]);
    }
  };
  stage(0, 0);
  int cur = 0;
  for (int kt = 0; kt < kmax; kt += 64) {
    if (kt + 64 < kmax) {
      stage(cur ^ 1, kt + 64);
      asm volatile("s_waitcnt vmcnt(4)" ::: "memory");
    } else {
      asm volatile("s_waitcnt vmcnt(0)" ::: "memory");
    }
    __builtin_amdgcn_s_barrier();
    __builtin_amdgcn_sched_barrier(0);
    #pragma unroll
    for (int h = 0; h < 2; h++) {
      int eo = (h * 32 + kq * 8) ^ ((lr & 7) << 3);
      bf16x8 af[4], bfr[2];
      #pragma unroll
      for (int i = 0; i < 4; i++)
        af[i] = *(const bf16x8*)&As[cur][(wm * 64 + i * 16 + lr) * 64 + eo];
      #pragma unroll
      for (int j = 0; j < 2; j++)
        bfr[j] = *(const bf16x8*)&Bs[cur][(wn * 32 + j * 16 + lr) * 64 + eo];
      #pragma unroll
      for (int i = 0; i < 4; i++)
        #pragma unroll
        for (int j = 0; j < 2; j++)
          acc[i][j] = __builtin_amdgcn_mfma_f32_16x16x32_bf16(af[i], bfr[j], acc[i][j], 0, 0, 0);
    }
    __builtin_amdgcn_s_barrier();
    cur ^= 1;
  }
  int t0 = c * 16;
  if (n0 < 8192) {
    int jm1 = n0 >> 9;              // 128-block never crosses a 512 boundary
    float* Zt = Zout + (long)(t0 + jm1) * 262144;
    for (int j = 0; j < 2; j++) {
      int n = n0 + wn * 32 + j * 16 + lr, dcol = n & 511;
      for (int i = 0; i < 4; i++)
        for (int r = 0; r < 4; r++) {
          int m = m0 + wm * 64 + i * 16 + kq * 4 + r;
          Zt[(long)m * 512 + dcol] = acc[i][j][r];
        }
    }
  } else {
    for (int j = 0; j < 2; j++) {
      int n = n0 + wn * 32 + j * 16 + lr;
      int q = n - 8192, jm1 = q >> 6, o = q & 63;
      if (o >= 50) continue;
      int t = t0 + jm1;
      for (int i = 0; i < 4; i++)
        for (int r = 0; r < 4; r++) {
          int m = m0 + wm * 64 + i * 16 + kq * 4 + r;
          Yout[((long)t * 512 + m) * 50 + o] = acc[i][j][r];
        }
    }
  }
}

// ---------------------------------------------------------------------------
// workspace layout (bytes)
// ---------------------------------------------------------------------------
static constexpr long NE2F = 331776L * 4;   // 576^2 f32      = 1,327,104
static constexpr long SPLT = 995328L * 2;   // 576*1728 bf16  = 1,990,656
// region A (expm scratch; only FF is read after the expm chain)
static constexpr long OFF_XF   = 0;
static constexpr long OFF_X2F  = OFF_XF   + NE2F;
static constexpr long OFF_X3F  = OFF_X2F  + NE2F;
static constexpr long OFF_B0F  = OFF_X3F  + NE2F;
static constexpr long OFF_XAP  = OFF_B0F  + NE2F;
static constexpr long OFF_XBT  = OFF_XAP  + SPLT;
static constexpr long OFF_X2AP = OFF_XBT  + SPLT;
static constexpr long OFF_X2BT = OFF_X2AP + SPLT;
static constexpr long OFF_X4BT = OFF_X2BT + SPLT;
static constexpr long OFF_B1AP = OFF_X4BT + SPLT;
static constexpr long OFF_EAP  = OFF_B1AP + SPLT;
static constexpr long OFF_EBT  = OFF_EAP  + SPLT;
static constexpr long OFF_FAP  = OFF_EBT  + SPLT;
static constexpr long OFF_FBT  = OFF_FAP  + SPLT;
static constexpr long OFF_FF   = OFF_FBT  + SPLT;     // 25.21M .. 26.54M
// region B aliases region A (temporally disjoint)
static constexpr long OFF_WBT  = 0;                            // 9216x1024 bf16 = 18,874,368
static constexpr long OFF_PT   = 18874368;                     // 16 x 512x512 bf16 = 8 MB
static constexpr long OFF_XB   = OFF_PT;                       // Xb aliases PT (PT dead first)
// small matrices ABOVE Xb span (Xb ends at 35,651,584)
static constexpr long OFF_BBT  = 35651584;                     // 32 KB
static constexpr long OFF_G    = OFF_BBT + 32768;              // 16 x 512x32 bf16
static constexpr long OFF_CA   = OFF_G   + 16L * 16384 * 2;    // 17 x 64x512 bf16
static constexpr long OFF_CG   = OFF_CA  + 17L * 32768 * 2;    // 16 x 64x32 bf16
// total: 37,388,288 bytes (within the 38.4MB footprint proven in round 0)

extern "C" void kernel_launch(void* const* d_in, const int* in_sizes, int n_in,
                              void* d_out, int out_size, void* d_ws, size_t ws_size,
                              hipStream_t stream){
  const float* z_dyn = (const float*)d_in[0];
  const float* dtp   = (const float*)d_in[2];
  const float* U     = (const float*)d_in[3];
  const float* skew  = (const float*)d_in[4];
  const float* gamma = (const float*)d_in[5];
  const float* B_ct  = (const float*)d_in[6];
  const float* Cin   = (const float*)d_in[7];
  const float* Din   = (const float*)d_in[8];
  float* Zout = (float*)d_out;
  float* Yout = Zout + 67108864L;   // 256*512*512

  char* ws = (char*)d_ws;
  float* Xf  = (float*)(ws + OFF_XF);
  float* X2f = (float*)(ws + OFF_X2F);
  float* X3f = (float*)(ws + OFF_X3F);
  float* B0f = (float*)(ws + OFF_B0F);
  float* Ff  = (float*)(ws + OFF_FF);
  unsigned short* XAp  = (unsigned short*)(ws + OFF_XAP);
  unsigned short* XBt  = (unsigned short*)(ws + OFF_XBT);
  unsigned short* X2Ap = (unsigned short*)(ws + OFF_X2AP);
  unsigned short* X2Bt = (unsigned short*)(ws + OFF_X2BT);
  unsigned short* X4Bt = (unsigned short*)(ws + OFF_X4BT);
  unsigned short* B1Ap = (unsigned short*)(ws + OFF_B1AP);
  unsigned short* EAp  = (unsigned short*)(ws + OFF_EAP);
  unsigned short* EBt  = (unsigned short*)(ws + OFF_EBT);
  unsigned short* FAp  = (unsigned short*)(ws + OFF_FAP);
  unsigned short* FBt  = (unsigned short*)(ws + OFF_FBT);
  unsigned short* WbigT = (unsigned short*)(ws + OFF_WBT);
  unsigned short* PT    = (unsigned short*)(ws + OFF_PT);
  unsigned short* BbarT = (unsigned short*)(ws + OFF_BBT);
  unsigned short* Gar   = (unsigned short*)(ws + OFF_G);
  unsigned short* CAb   = (unsigned short*)(ws + OFF_CA);
  unsigned short* CGb   = (unsigned short*)(ws + OFF_CG);
  unsigned short* Xb    = (unsigned short*)(ws + OFF_XB);

  // scratch inside d_out (dead before k_mmbig overwrites all of Z and Y)
  unsigned short* Sb  = (unsigned short*)Yout;   // 16 x 512x512 bf16 (ld512)
  unsigned short* M2b = Sb  + 4194304;           // A^32 row-major (ld512)
  unsigned short* TM2 = M2b + 262144;
  unsigned short* M4b = TM2 + 262144;
  unsigned short* TM4 = M4b + 262144;
  unsigned short* M8b = TM4 + 262144;

  dim3 b256(256);
  const long WBLK = 524288;  // 512*1024 elements
  const long PBLK = 262144;  // 512*512 elements
  unsigned short* Wlast = WbigT + 15L * WBLK;
  const unsigned short* NUL = nullptr;

  // ---- expm(Maug*dt): scaling s=2 + degree-7 PS Taylor ----
  k_build_M<<<dim3(324), b256, 0, stream>>>(skew, gamma, dtp, B_ct, Xf, XAp, XBt);
  k_expm_gemm<<<dim3(18,18,1), b256, 0, stream>>>(XAp, XBt, nullptr, X2f, X2Ap, X2Bt,
                                                  NUL, NUL, nullptr, nullptr, nullptr, nullptr); // X2
  k_expm_gemm<<<dim3(18,18,2), b256, 0, stream>>>(X2Ap, XBt,  nullptr, X3f, nullptr, nullptr,
                                                  X2Ap, X2Bt, nullptr, nullptr, nullptr, X4Bt);  // X3 | X4
  k_poly<<<dim3(1296), b256, 0, stream>>>(Xf, X2f, X3f, B0f, B1Ap);
  k_expm_gemm<<<dim3(18,18,1), b256, 0, stream>>>(B1Ap, X4Bt, B0f, nullptr, EAp, EBt,
                                                  NUL, NUL, nullptr, nullptr, nullptr, nullptr); // E
  k_expm_gemm<<<dim3(18,18,1), b256, 0, stream>>>(EAp, EBt, nullptr, nullptr, FAp, FBt,
                                                  NUL, NUL, nullptr, nullptr, nullptr, nullptr); // F = E^2
  k_expm_gemm<<<dim3(18,18,1), b256, 0, stream>>>(FAp, FBt, nullptr, Ff, nullptr, nullptr,
                                                  NUL, NUL, nullptr, nullptr, nullptr, nullptr); // Ff = F^2

  // ---- extract A_bar/B_bar, padded C ----
  k_extract<<<dim3(260), b256, 0, stream>>>(Ff, Cin, WbigT, PT, BbarT, Gar, CAb);

  // ---- powers of A by doubling (transpose fused via outT -> PT blocks) ----
  k_btgemm<64,64,2,2><<<dim3(8,8,1), b256, 0, stream>>>(WbigT, 1024, 0, PT, 512, 0, WbigT + WBLK, 1024, 0, 512, PT + PBLK, 512, 0);
  k_btgemm<64,64,2,2><<<dim3(8,8,2), b256, 0, stream>>>(WbigT + WBLK, 1024, 0, PT, 512, PBLK, WbigT + 2*WBLK, 1024, WBLK, 512, PT + 2*PBLK, 512, PBLK);
  k_btgemm<64,64,2,2><<<dim3(8,8,4), b256, 0, stream>>>(WbigT + 3*WBLK, 1024, 0, PT, 512, PBLK, WbigT + 4*WBLK, 1024, WBLK, 512, PT + 4*PBLK, 512, PBLK);
  k_btgemm<64,64,2,2><<<dim3(8,8,8), b256, 0, stream>>>(WbigT + 7*WBLK, 1024, 0, PT, 512, PBLK, WbigT + 8*WBLK, 1024, WBLK, 512, PT + 8*PBLK, 512, PBLK);

  // ---- prefix-scan powers A^32/A^64/A^128 (PT15/PT16 still live) ----
  k_btgemm<64,64,2,2><<<dim3(8,8,1), b256, 0, stream>>>(Wlast, 1024, 0, PT + 15*PBLK, 512, 0, M2b, 512, 0, 512, TM2, 512, 0);
  k_btgemm<64,64,2,2><<<dim3(8,8,1), b256, 0, stream>>>(M2b, 512, 0, TM2, 512, 0, M4b, 512, 0, 512, TM4, 512, 0);
  k_btgemm<64,64,2,2><<<dim3(8,8,1), b256, 0, stream>>>(M4b, 512, 0, TM4, 512, 0, M8b, 512, 0, 512, nullptr, 0, 0);

  // ---- merged: G_1..15 (z<15) + CA_1..8 (z>=15) ----
  k_gca<<<dim3(16, 8, 23), b256, 0, stream>>>(WbigT, BbarT, CAb, PT, Gar + 16384, CAb + 32768);
  // CA9..16 = CA1..8 @ A^8
  k_btgemm<64,64,2,2><<<dim3(8,1,8), b256, 0, stream>>>(CAb + 32768, 512, 32768, PT + 7*PBLK, 512, 0, CAb + 9L*32768, 512, 32768, 512, nullptr, 0, 0);

  // ---- merged: CG_0..15 + packX (packX clobbers only dead PT) ----
  k_cgpack<<<dim3(4368), b256, 0, stream>>>(CAb, BbarT, CGb, z_dyn, U, Xb);

  // ---- assemble W (U+Y regions) ----
  k_assembleUW<<<dim3(5120), b256, 0, stream>>>(Gar, CAb, CGb, Din, dtp, WbigT);

  // ---- Ubar_c = U_c @ GU^T -> init S[c+1] (bf16 into Xb z0-slots) ----
  k_btgemm<64,64,2,2><<<dim3(8,8,15), b256, 0, stream>>>(
      Xb + 512, 1024, WBLK, Wlast + 512, 1024, 0,
      Xb + WBLK, 1024, WBLK, 512, nullptr, 0, 0);

  // ---- Hillis-Steele: 4 rounds, bf16 ping-pong ----
  k_scanround<<<dim3(8,8,16), b256, 0, stream>>>(Xb, 1024, WBLK, Wlast, 1024, Sb, 512, PBLK, 1);
  k_scanround<<<dim3(8,8,16), b256, 0, stream>>>(Sb, 512, PBLK, M2b, 512, Xb, 1024, WBLK, 2);
  k_scanround<<<dim3(8,8,16), b256, 0, stream>>>(Xb, 1024, WBLK, M4b, 512, Sb, 512, PBLK, 4);
  k_scanround<<<dim3(8,8,16), b256, 0, stream>>>(Sb, 512, PBLK, M8b, 512, Xb, 1024, WBLK, 8);

  // ---- ONE parallel dispatch: all 16 chunks, Z + Y, K-skipped ----
  k_mmbig<<<dim3(72, 4, 16), dim3(512), 0, stream>>>(Xb, WbigT, Zout, Yout);
}